// Round 2
// baseline (87.403 us; speedup 1.0000x reference)
//
#include <hip/hip_runtime.h>
#include <hip/hip_bf16.h>

// The entire attention branch of the reference reduces to the constant 1.0
// (softmax over a size-1 axis -> ones; attn rows sum to 1). Only the
// "local" branch survives:
//   out[b, o*576 + p] = 1 + gelu( conv3x3(x4, local_w, groups=2, pad=1)*s[o] + t[o] )
// with s[o] = bnc1_gamma[o]*rsqrt(1+eps), t[o] = bnc1_beta[o], NCHW flat order
// (c.reshape(b,N,DIM) is a flat reinterpretation of NCHW, no transpose).
// All tensors are float32 per the reference.

__global__ __launch_bounds__(576, 1) void fused_conv_gelu(
    const float* __restrict__ x,    // (2,128,24,24) flat
    const float* __restrict__ lw,   // (128,64,3,3) flat
    const float* __restrict__ gam,  // (128,)
    const float* __restrict__ bet,  // (128,)
    float* __restrict__ out)        // (2,576,128) flat == (2,128,24,24) flat
{
    const int bi = blockIdx.x;          // 0..255 -> (b, o)
    const int b  = bi >> 7;
    const int o  = bi & 127;
    const int g  = o >> 6;              // group: input channels g*64 .. g*64+63
    const int p  = threadIdx.x;         // 0..575 spatial position
    const int h  = p / 24;
    const int w  = p - h * 24;

    const float* __restrict__ xb = x  + (b * 128 + g * 64) * 576;
    const float* __restrict__ wb = lw + o * 576;

    // tap validity masks (channel-invariant)
    bool val[9];
#pragma unroll
    for (int dh = 0; dh < 3; ++dh)
#pragma unroll
        for (int dw = 0; dw < 3; ++dw) {
            const int hh = h + dh - 1, ww = w + dw - 1;
            val[dh * 3 + dw] = (hh >= 0) && (hh < 24) && (ww >= 0) && (ww < 24);
        }

    float acc = 0.0f;

    // i = 0 and i = 63: clamped addressing keeps every load inside the
    // buffer (i=0 underflows at the low edge, i=63 overflows at the high
    // edge for b=1,g=1).
#pragma unroll
    for (int ic = 0; ic < 2; ++ic) {
        const int i = ic ? 63 : 0;
        const float* __restrict__ xi = xb + i * 576;
        const float* __restrict__ wi = wb + i * 9;
#pragma unroll
        for (int dh = 0; dh < 3; ++dh)
#pragma unroll
            for (int dw = 0; dw < 3; ++dw) {
                const int t  = dh * 3 + dw;
                const int hh = min(max(h + dh - 1, 0), 23);
                const int ww = min(max(w + dw - 1, 0), 23);
                const float xv = xi[hh * 24 + ww];
                acc = fmaf(val[t] ? xv : 0.0f, wi[t], acc);
            }
    }

    // i = 1..62: compile-time tap offsets. Address range relative to xb is
    // [576 + 0 - 25, 62*576 + 575 + 25] = [551, 36312] -- always in-bounds.
    // Out-of-window taps read neighboring-channel data and are zeroed by
    // the select (unconditional load -> v_cndmask, no divergence).
#pragma unroll 2
    for (int i = 1; i < 63; ++i) {
        const float* __restrict__ xi = xb + i * 576 + p;
        const float* __restrict__ wi = wb + i * 9;
#pragma unroll
        for (int dh = 0; dh < 3; ++dh)
#pragma unroll
            for (int dw = 0; dw < 3; ++dw) {
                const int t  = dh * 3 + dw;
                const float xv = xi[(dh - 1) * 24 + (dw - 1)];
                acc = fmaf(val[t] ? xv : 0.0f, wi[t], acc);
            }
    }

    // BN (inference form) + exact gelu + the attention-branch constant 1.0
    const float scale = gam[o] * rsqrtf(1.0f + 1e-5f);
    const float shift = bet[o];
    const float y  = fmaf(acc, scale, shift);
    const float gl = 0.5f * y * (1.0f + erff(y * 0.70710678118654752f));
    out[b * 73728 + o * 576 + p] = 1.0f + gl;
}

extern "C" void kernel_launch(void* const* d_in, const int* in_sizes, int n_in,
                              void* d_out, int out_size, void* d_ws, size_t ws_size,
                              hipStream_t stream) {
    const float* x   = (const float*)d_in[0];   // x
    const float* lw  = (const float*)d_in[9];   // local_w
    const float* gam = (const float*)d_in[10];  // bnc1_gamma
    const float* bet = (const float*)d_in[11];  // bnc1_beta
    float* out = (float*)d_out;

    fused_conv_gelu<<<dim3(256), dim3(576), 0, stream>>>(x, lw, gam, bet, out);
}